// Round 14
// baseline (893.625 us; speedup 1.0000x reference)
//
#include <hip/hip_runtime.h>
#include <hip/hip_bf16.h>
#include <cmath>

// Problem: N=64, T=512, D=256, H=256 (all fp32)
//   c   = x @ Wx + b          (N,T,H)  -- parallel GEMM
//   h_t = tanh(c_t + h_{t-1} @ Wh)     -- sequential scan
// Output: all h_t, (N,T,H).
//
// Round-14 = Round-13 with the offset fix: gfx950 global_load immediate
// offset is 13-bit SIGNED (max +4095); R13's offset:4096..7168 failed to
// assemble. Now TWO base regs (wbase, wbase+4096B), offsets 0..3072 each.
//
// Theory unchanged (R13): take scheduling away from the compiler. R12
// proved the backend serializes C-level load clusters at its 36-reg
// pressure target (load->wait->consume x8, ~250cy exposed each => 819us).
// Scan FMA phase in explicit asm:
//   asm1: 8x global_load_dwordx4 into "=&v" uint4s (allocator MUST give
//         32 VGPRs -- asm operands are non-negotiable).
//   asm2 (x8): s_waitcnt vmcnt(7-k) + 8 v_fma_mix_f32 (group k).
// W loads are always the newest 8 VMEM ops of the wave, so vmcnt(7-k)
// is correct under any interleave with c-prefetch / h-store. Volatile
// asm blocks keep mutual order; wait+consume share a block (no hoisting).
//  - fp16 pre-packed Wh in __device__ global (128 KB, L2-resident).
//  - Fusion topology (R6) and GEMM unchanged.

#define KDIM  256
#define HDIM  256
#define TSTEPS 512
#define NBATCH 64
#define SCAN_BLOCKS 64
#define CH_STEPS 64            // t-steps per chunk
#define NCH 8                  // chunks per row
#define GEMM_BLOCKS (NCH * NBATCH)   // 512
#define SMEM_BYTES 41984       // max(scan 17408, gemm 8704+33280)

// Packed Wh: uint4 index (g*8+p)*64 + jq, component q = column 4*jq+q,
// value = pack2(Wh[16g+2p][col], Wh[16g+2p+1][col]).  128 KB total.
__device__ uint4 g_Wp[8192];

__device__ __forceinline__ unsigned pack2(float lo, float hi) {
    _Float16 fa = (_Float16)lo, fb = (_Float16)hi;   // RTE converts
    unsigned short a, b;
    __builtin_memcpy(&a, &fa, 2);
    __builtin_memcpy(&b, &fb, 2);
    return (unsigned)a | ((unsigned)b << 16);
}

__global__ __launch_bounds__(256) void pack_wh(const float* __restrict__ Wh) {
    int idx = blockIdx.x * 256 + threadIdx.x;   // 0..8191
    int jq = idx & 63;
    int gp = idx >> 6;                          // 0..127
    int g = gp >> 3, p = gp & 7;
    const float* r0 = Wh + (size_t)(g * 16 + 2 * p) * HDIM + jq * 4;
    const float* r1 = r0 + HDIM;
    uint4 o;
    o.x = pack2(r0[0], r1[0]);
    o.y = pack2(r0[1], r1[1]);
    o.z = pack2(r0[2], r1[2]);
    o.w = pack2(r0[3], r1[3]);
    g_Wp[idx] = o;
}

// Group k: wait for load k (W loads are the newest 8 VMEM ops -> vmcnt(7-k)
// guarantees load k complete), then 8 v_fma_mix_f32:
//   acc_q += HLO * lo(T.q) + HHI * hi(T.q)
#define FMAGRP(VM, HLO, HHI, T)                                                \
    asm volatile(                                                              \
        "s_waitcnt vmcnt(" #VM ")\n\t"                                         \
        "v_fma_mix_f32 %0, %4, %6, %0 op_sel:[0,0,0] op_sel_hi:[0,1,0]\n\t"    \
        "v_fma_mix_f32 %0, %5, %6, %0 op_sel:[0,1,0] op_sel_hi:[0,1,0]\n\t"    \
        "v_fma_mix_f32 %1, %4, %7, %1 op_sel:[0,0,0] op_sel_hi:[0,1,0]\n\t"    \
        "v_fma_mix_f32 %1, %5, %7, %1 op_sel:[0,1,0] op_sel_hi:[0,1,0]\n\t"    \
        "v_fma_mix_f32 %2, %4, %8, %2 op_sel:[0,0,0] op_sel_hi:[0,1,0]\n\t"    \
        "v_fma_mix_f32 %2, %5, %8, %2 op_sel:[0,1,0] op_sel_hi:[0,1,0]\n\t"    \
        "v_fma_mix_f32 %3, %4, %9, %3 op_sel:[0,0,0] op_sel_hi:[0,1,0]\n\t"    \
        "v_fma_mix_f32 %3, %5, %9, %3 op_sel:[0,1,0] op_sel_hi:[0,1,0]\n\t"    \
        : "+v"(a0), "+v"(a1), "+v"(a2), "+v"(a3)                               \
        : "v"(HLO), "v"(HHI), "v"(T.x), "v"(T.y), "v"(T.z), "v"(T.w))

// mode: 0 = fused (flags valid), 1 = gemm-only (no signal), 2 = scan-only (no wait)
__global__ __launch_bounds__(1024) void fused(
    const float* __restrict__ x,    // (32768, 256)
    const float* __restrict__ h0v,  // (64, 256)
    const float* __restrict__ Wx,   // (256, 256)
    const float* __restrict__ bias, // (256)
    float* __restrict__ out,        // (64, 512, 256): c, overwritten by h
    unsigned int* flags,            // (64, 8) in d_ws
    int mode)
{
    __shared__ __align__(16) char smem[SMEM_BYTES];
    const int tid = threadIdx.x;

    if (mode == 1 && blockIdx.x < SCAN_BLOCKS) return;   // gemm-only pass
    const bool is_scan = (mode == 2) || (mode == 0 && blockIdx.x < SCAN_BLOCKS);

    if (!is_scan) {
        // ======================= GEMM: 64m x 256n tile =======================
        float (*As)[68]  = (float(*)[68])smem;            // [k][m] transposed
        float (*Bs)[260] = (float(*)[260])(smem + 8704);  // [k][n]

        const int bm = (int)blockIdx.x - SCAN_BLOCKS;     // 0..511
        const int r  = bm & 63;
        const int ch = bm >> 6;                           // ch-major dispatch
        const int m0 = r * TSTEPS + ch * CH_STEPS;
        const int tx = tid & 63;                          // 4 cols each
        const int ty = tid >> 6;                          // 0..15, 4 rows each

        float acc[4][4];
#pragma unroll
        for (int i = 0; i < 4; ++i)
#pragma unroll
            for (int j = 0; j < 4; ++j) acc[i][j] = 0.f;

        for (int kc = 0; kc < KDIM; kc += 32) {
            if (tid < 512) {                              // stage A transposed
                int arow = tid >> 3;                      // 0..63 (m)
                int ac4  = (tid & 7) << 2;                // 0..28 (k)
                float4 va = *(const float4*)&x[(size_t)(m0 + arow) * KDIM + kc + ac4];
                As[ac4 + 0][arow] = va.x;
                As[ac4 + 1][arow] = va.y;
                As[ac4 + 2][arow] = va.z;
                As[ac4 + 3][arow] = va.w;
            }
            {                                             // stage B (2 rows/thread)
                int brow = tid >> 6;                      // 0..15 (k)
                int bc4  = (tid & 63) << 2;               // 0..252 (n)
                *(float4*)&Bs[brow][bc4] =
                    *(const float4*)&Wx[(size_t)(kc + brow) * HDIM + bc4];
                *(float4*)&Bs[brow + 16][bc4] =
                    *(const float4*)&Wx[(size_t)(kc + brow + 16) * HDIM + bc4];
            }
            __syncthreads();

#pragma unroll
            for (int kk = 0; kk < 32; ++kk) {
                float4 a = *(const float4*)&As[kk][ty * 4];  // wave-uniform (bcast)
                float4 b = *(const float4*)&Bs[kk][tx * 4];
                acc[0][0] += a.x * b.x; acc[0][1] += a.x * b.y;
                acc[0][2] += a.x * b.z; acc[0][3] += a.x * b.w;
                acc[1][0] += a.y * b.x; acc[1][1] += a.y * b.y;
                acc[1][2] += a.y * b.z; acc[1][3] += a.y * b.w;
                acc[2][0] += a.z * b.x; acc[2][1] += a.z * b.y;
                acc[2][2] += a.z * b.z; acc[2][3] += a.z * b.w;
                acc[3][0] += a.w * b.x; acc[3][1] += a.w * b.y;
                acc[3][2] += a.w * b.z; acc[3][3] += a.w * b.w;
            }
            __syncthreads();
        }

        float4 bj = *(const float4*)&bias[tx * 4];
#pragma unroll
        for (int i = 0; i < 4; ++i) {
            float4 v;
            v.x = acc[i][0] + bj.x;
            v.y = acc[i][1] + bj.y;
            v.z = acc[i][2] + bj.z;
            v.w = acc[i][3] + bj.w;
            *(float4*)&out[(size_t)(m0 + ty * 4 + i) * HDIM + tx * 4] = v;
        }

        if (mode == 0) {
            __syncthreads();    // all stores program-ordered before signal (hb)
            if (tid == 0)
                __hip_atomic_fetch_add(&flags[r * NCH + ch], 1u,
                                       __ATOMIC_RELEASE, __HIP_MEMORY_SCOPE_AGENT);
        }
        return;
    }

    // ==== SCAN: fp16 W streamed via explicit asm loads + counted vmcnt ====
    float* h = (float*)smem;                          // 256 floats
    float (*red)[256] = (float(*)[256])(smem + 1024); // [16][256] partials

    const int r   = (int)blockIdx.x;
    const int jq  = tid & 63;       // column quad
    const int g   = tid >> 6;       // k-group (0..15)
    const int j0  = jq << 2;

    const uint4* wbase  = g_Wp + (size_t)(g * 8) * 64 + jq;
    const uint4* wbase2 = wbase + 256;     // +4096 B (13-bit signed imm limit)

    if (tid < 256) h[tid] = h0v[(size_t)r * HDIM + tid];

    float* outr = out + (size_t)r * TSTEPS * HDIM;
    __syncthreads();

    float c_next = 0.f;
    for (int ch = 0; ch < NCH; ++ch) {
        if (mode == 0) {
            if (tid == 0) {
                const unsigned int* f = &flags[r * NCH + ch];
                while (__hip_atomic_load(f, __ATOMIC_RELAXED,
                                         __HIP_MEMORY_SCOPE_AGENT) == 0u)
                    __builtin_amdgcn_s_sleep(8);
                (void)__hip_atomic_load(f, __ATOMIC_ACQUIRE,
                                        __HIP_MEMORY_SCOPE_AGENT);
            }
            __syncthreads();    // acquire happens-before everyone's c reads
        }
        if (g < 4) c_next = outr[(size_t)(ch * CH_STEPS) * HDIM + tid];

        for (int tt = 0; tt < CH_STEPS; ++tt) {
            const int t = ch * CH_STEPS + tt;
            float c = c_next;
            if (g < 4 && tt + 1 < CH_STEPS)     // stay inside gated chunk
                c_next = outr[(size_t)(t + 1) * HDIM + tid];

            const float4* hv = (const float4*)(h + (g << 4));
            float4 ha = hv[0], hb = hv[1], hc = hv[2], hd = hv[3];

            // Issue ALL 8 W loads in one asm block (allocator must give 32
            // VGPRs; no scheduler can serialize the cluster). Two base regs
            // because the immediate offset is 13-bit signed (max +4095).
            uint4 t0, t1, t2, t3, t4, t5, t6, t7;
            asm volatile(
                "global_load_dwordx4 %0, %8, off\n\t"
                "global_load_dwordx4 %1, %8, off offset:1024\n\t"
                "global_load_dwordx4 %2, %8, off offset:2048\n\t"
                "global_load_dwordx4 %3, %8, off offset:3072\n\t"
                "global_load_dwordx4 %4, %9, off\n\t"
                "global_load_dwordx4 %5, %9, off offset:1024\n\t"
                "global_load_dwordx4 %6, %9, off offset:2048\n\t"
                "global_load_dwordx4 %7, %9, off offset:3072\n\t"
                : "=&v"(t0), "=&v"(t1), "=&v"(t2), "=&v"(t3),
                  "=&v"(t4), "=&v"(t5), "=&v"(t6), "=&v"(t7)
                : "v"(wbase), "v"(wbase2));

            float a0 = 0.f, a1 = 0.f, a2 = 0.f, a3 = 0.f;
            FMAGRP(7, ha.x, ha.y, t0);   // k 0,1
            FMAGRP(6, ha.z, ha.w, t1);   // k 2,3
            FMAGRP(5, hb.x, hb.y, t2);   // k 4,5
            FMAGRP(4, hb.z, hb.w, t3);   // k 6,7
            FMAGRP(3, hc.x, hc.y, t4);   // k 8,9
            FMAGRP(2, hc.z, hc.w, t5);   // k 10,11
            FMAGRP(1, hd.x, hd.y, t6);   // k 12,13
            FMAGRP(0, hd.z, hd.w, t7);   // k 14,15

            float4 accv; accv.x = a0; accv.y = a1; accv.z = a2; accv.w = a3;
            *(float4*)&red[g][j0] = accv;
            __syncthreads();

            if (tid < 256) {
                float s0 = red[0][tid] + red[1][tid];
                float s1 = red[2][tid] + red[3][tid];
                float s2 = red[4][tid] + red[5][tid];
                float s3 = red[6][tid] + red[7][tid];
                float s4 = red[8][tid] + red[9][tid];
                float s5 = red[10][tid] + red[11][tid];
                float s6 = red[12][tid] + red[13][tid];
                float s7 = red[14][tid] + red[15][tid];
                float s  = (((s0 + s1) + (s2 + s3)) + ((s4 + s5) + (s6 + s7))) + c;
                float e  = __expf(2.f * s);
                float hn = 1.f - 2.f / (e + 1.f);
                outr[(size_t)t * HDIM + tid] = hn;
                h[tid] = hn;
            }
            __syncthreads();
        }
    }
}

extern "C" void kernel_launch(void* const* d_in, const int* in_sizes, int n_in,
                              void* d_out, int out_size, void* d_ws, size_t ws_size,
                              hipStream_t stream) {
    const float* x  = (const float*)d_in[0];   // (64,512,256)
    const float* h0 = (const float*)d_in[1];   // (64,256)
    const float* Wx = (const float*)d_in[2];   // (256,256)
    const float* Wh = (const float*)d_in[3];   // (256,256)
    const float* b  = (const float*)d_in[4];   // (256)
    float* out = (float*)d_out;                // (64,512,256)

    // Pre-pack Wh -> fp16 pairs in g_Wp (device global; no ws needed).
    pack_wh<<<32, 256, 0, stream>>>(Wh);

    const size_t flag_bytes = (size_t)NBATCH * NCH * sizeof(unsigned int);
    if (d_ws != nullptr && ws_size >= flag_bytes) {
        unsigned int* flags = (unsigned int*)d_ws;
        hipMemsetAsync(d_ws, 0, flag_bytes, stream);
        fused<<<SCAN_BLOCKS + GEMM_BLOCKS, 1024, 0, stream>>>(
            x, h0, Wx, b, out, flags, 0);
    } else {
        // Fallback: serialized two-pass.
        fused<<<SCAN_BLOCKS + GEMM_BLOCKS, 1024, 0, stream>>>(
            x, h0, Wx, b, out, nullptr, 1);
        fused<<<SCAN_BLOCKS, 1024, 0, stream>>>(
            x, h0, Wx, b, out, nullptr, 2);
    }
}

// Round 15
// 655.277 us; speedup vs baseline: 1.3637x; 1.3637x over previous
//
#include <hip/hip_runtime.h>
#include <hip/hip_bf16.h>
#include <cmath>

// Problem: N=64, T=512, D=256, H=256 (all fp32)
//   c   = x @ Wx + b          (N,T,H)  -- parallel GEMM
//   h_t = tanh(c_t + h_{t-1} @ Wh)     -- sequential scan
// Output: all h_t, (N,T,H).
//
// Round-15: revert to the best-known-good (R6: fused, fp32 FMA16 asm,
// 409us dispatch) and pull the ONE unexploited lever: AMORTIZE THE W
// STREAM OVER 2 BATCH ROWS PER BLOCK. R7-R14 proved the W stream itself
// cannot be improved (resident-W always spilled; fp16/v_fma_mix slower;
// asm clusters starved the rest of the kernel). But each W fetch can feed
// 2 rows' FMAs: 32 scan blocks, block b owns rows 2b,2b+1; per-thread W
// slice (64 fp32, pin-then-spill = the proven R6 stream) now does 128
// FMAs -> W bytes PER ROW halve. Step ~1900cy/2rows vs R6's 1670cy/row.
//  - Scan LDS: h[512] + red[2][16][256] = 34.8KB (< GEMM's 42KB).
//  - Flags: scan block waits on BOTH rows' chunk flags.
//  - GEMM, fusion protocol, numerics: identical to R6.

#define KDIM  256
#define HDIM  256
#define TSTEPS 512
#define NBATCH 64
#define SCAN_BLOCKS 32         // 2 rows per block
#define ROWS_PB 2
#define CH_STEPS 64            // t-steps per chunk
#define NCH 8                  // chunks per row
#define GEMM_BLOCKS (NCH * NBATCH)   // 512
#define SMEM_BYTES 41984       // max(scan 34816, gemm 8704+33280)

// 16 chained v_fmac_f32: ACC += h_k * w_k  (k = 0..15).  (R5/R6 proven)
#define FMA16(ACC, W0,W1,W2,W3,W4,W5,W6,W7,W8,W9,W10,W11,W12,W13,W14,W15)   \
    asm("v_fmac_f32 %0, %1, %17\n\t"                                        \
        "v_fmac_f32 %0, %2, %18\n\t"                                        \
        "v_fmac_f32 %0, %3, %19\n\t"                                        \
        "v_fmac_f32 %0, %4, %20\n\t"                                        \
        "v_fmac_f32 %0, %5, %21\n\t"                                        \
        "v_fmac_f32 %0, %6, %22\n\t"                                        \
        "v_fmac_f32 %0, %7, %23\n\t"                                        \
        "v_fmac_f32 %0, %8, %24\n\t"                                        \
        "v_fmac_f32 %0, %9, %25\n\t"                                        \
        "v_fmac_f32 %0, %10, %26\n\t"                                       \
        "v_fmac_f32 %0, %11, %27\n\t"                                       \
        "v_fmac_f32 %0, %12, %28\n\t"                                       \
        "v_fmac_f32 %0, %13, %29\n\t"                                       \
        "v_fmac_f32 %0, %14, %30\n\t"                                       \
        "v_fmac_f32 %0, %15, %31\n\t"                                       \
        "v_fmac_f32 %0, %16, %32\n\t"                                       \
        : "+v"(ACC)                                                         \
        : "v"(h0), "v"(h1), "v"(h2), "v"(h3),                               \
          "v"(h4), "v"(h5), "v"(h6), "v"(h7),                               \
          "v"(h8), "v"(h9), "v"(h10), "v"(h11),                             \
          "v"(h12), "v"(h13), "v"(h14), "v"(h15),                           \
          "v"(W0), "v"(W1), "v"(W2), "v"(W3),                               \
          "v"(W4), "v"(W5), "v"(W6), "v"(W7),                               \
          "v"(W8), "v"(W9), "v"(W10), "v"(W11),                             \
          "v"(W12), "v"(W13), "v"(W14), "v"(W15))

#define LDW(K)                                                              \
    float4 t##K = *(const float4*)(wp + (K) * HDIM);                        \
    float wA##K = t##K.x, wB##K = t##K.y, wC##K = t##K.z, wD##K = t##K.w;

#define PIN16(P)                                                            \
    asm volatile("" : "+v"(P##0), "+v"(P##1), "+v"(P##2), "+v"(P##3),       \
                      "+v"(P##4), "+v"(P##5), "+v"(P##6), "+v"(P##7),       \
                      "+v"(P##8), "+v"(P##9), "+v"(P##10), "+v"(P##11),     \
                      "+v"(P##12), "+v"(P##13), "+v"(P##14), "+v"(P##15))

// Load 16 h broadcasts for k-group g of row base HB (LDS pointer).
#define LDH(HB)                                                             \
    do {                                                                    \
        const float4* hv = (const float4*)((HB) + (g << 4));                \
        float4 ha = hv[0], hb = hv[1], hc = hv[2], hd = hv[3];              \
        h0 = ha.x; h1 = ha.y; h2 = ha.z; h3 = ha.w;                         \
        h4 = hb.x; h5 = hb.y; h6 = hb.z; h7 = hb.w;                         \
        h8 = hc.x; h9 = hc.y; h10 = hc.z; h11 = hc.w;                       \
        h12 = hd.x; h13 = hd.y; h14 = hd.z; h15 = hd.w;                     \
    } while (0)

#define FMA64(A0, A1, A2, A3)                                               \
    FMA16(A0, wA0,wA1,wA2,wA3,wA4,wA5,wA6,wA7,wA8,wA9,wA10,wA11,wA12,wA13,wA14,wA15); \
    FMA16(A1, wB0,wB1,wB2,wB3,wB4,wB5,wB6,wB7,wB8,wB9,wB10,wB11,wB12,wB13,wB14,wB15); \
    FMA16(A2, wC0,wC1,wC2,wC3,wC4,wC5,wC6,wC7,wC8,wC9,wC10,wC11,wC12,wC13,wC14,wC15); \
    FMA16(A3, wD0,wD1,wD2,wD3,wD4,wD5,wD6,wD7,wD8,wD9,wD10,wD11,wD12,wD13,wD14,wD15)

// mode: 0 = fused (flags valid), 1 = gemm-only (no signal), 2 = scan-only (no wait)
__global__ __launch_bounds__(1024) void fused(
    const float* __restrict__ x,    // (32768, 256)
    const float* __restrict__ h0v,  // (64, 256)
    const float* __restrict__ Wx,   // (256, 256)
    const float* __restrict__ Wh,   // (256, 256)
    const float* __restrict__ bias, // (256)
    float* __restrict__ out,        // (64, 512, 256): c, overwritten by h
    unsigned int* flags,            // (64, 8) in d_ws
    int mode)
{
    __shared__ __align__(16) char smem[SMEM_BYTES];
    const int tid = threadIdx.x;

    if (mode == 1 && blockIdx.x < SCAN_BLOCKS) return;   // gemm-only pass
    const bool is_scan = (mode == 2) || (mode == 0 && blockIdx.x < SCAN_BLOCKS);

    if (!is_scan) {
        // ======================= GEMM: 64m x 256n tile =======================
        float (*As)[68]  = (float(*)[68])smem;            // [k][m] transposed
        float (*Bs)[260] = (float(*)[260])(smem + 8704);  // [k][n]

        const int bm = (int)blockIdx.x - SCAN_BLOCKS;     // 0..511
        const int r  = bm & 63;
        const int ch = bm >> 6;                           // ch-major dispatch
        const int m0 = r * TSTEPS + ch * CH_STEPS;
        const int tx = tid & 63;                          // 4 cols each
        const int ty = tid >> 6;                          // 0..15, 4 rows each

        float acc[4][4];
#pragma unroll
        for (int i = 0; i < 4; ++i)
#pragma unroll
            for (int j = 0; j < 4; ++j) acc[i][j] = 0.f;

        for (int kc = 0; kc < KDIM; kc += 32) {
            if (tid < 512) {                              // stage A transposed
                int arow = tid >> 3;                      // 0..63 (m)
                int ac4  = (tid & 7) << 2;                // 0..28 (k)
                float4 va = *(const float4*)&x[(size_t)(m0 + arow) * KDIM + kc + ac4];
                As[ac4 + 0][arow] = va.x;
                As[ac4 + 1][arow] = va.y;
                As[ac4 + 2][arow] = va.z;
                As[ac4 + 3][arow] = va.w;
            }
            {                                             // stage B (2 rows/thread)
                int brow = tid >> 6;                      // 0..15 (k)
                int bc4  = (tid & 63) << 2;               // 0..252 (n)
                *(float4*)&Bs[brow][bc4] =
                    *(const float4*)&Wx[(size_t)(kc + brow) * HDIM + bc4];
                *(float4*)&Bs[brow + 16][bc4] =
                    *(const float4*)&Wx[(size_t)(kc + brow + 16) * HDIM + bc4];
            }
            __syncthreads();

#pragma unroll
            for (int kk = 0; kk < 32; ++kk) {
                float4 a = *(const float4*)&As[kk][ty * 4];  // wave-uniform (bcast)
                float4 b = *(const float4*)&Bs[kk][tx * 4];
                acc[0][0] += a.x * b.x; acc[0][1] += a.x * b.y;
                acc[0][2] += a.x * b.z; acc[0][3] += a.x * b.w;
                acc[1][0] += a.y * b.x; acc[1][1] += a.y * b.y;
                acc[1][2] += a.y * b.z; acc[1][3] += a.y * b.w;
                acc[2][0] += a.z * b.x; acc[2][1] += a.z * b.y;
                acc[2][2] += a.z * b.z; acc[2][3] += a.z * b.w;
                acc[3][0] += a.w * b.x; acc[3][1] += a.w * b.y;
                acc[3][2] += a.w * b.z; acc[3][3] += a.w * b.w;
            }
            __syncthreads();
        }

        float4 bj = *(const float4*)&bias[tx * 4];
#pragma unroll
        for (int i = 0; i < 4; ++i) {
            float4 v;
            v.x = acc[i][0] + bj.x;
            v.y = acc[i][1] + bj.y;
            v.z = acc[i][2] + bj.z;
            v.w = acc[i][3] + bj.w;
            *(float4*)&out[(size_t)(m0 + ty * 4 + i) * HDIM + tx * 4] = v;
        }

        if (mode == 0) {
            __syncthreads();    // all stores program-ordered before signal (hb)
            if (tid == 0)
                __hip_atomic_fetch_add(&flags[r * NCH + ch], 1u,
                                       __ATOMIC_RELEASE, __HIP_MEMORY_SCOPE_AGENT);
        }
        return;
    }

    // ============ SCAN: 2 rows/block, W stream amortized over both ============
    float* hl = (float*)smem;                            // [2][256]
    float (*red)[16][256] = (float(*)[16][256])(smem + 2048); // [2][16][256]

    const int b   = (int)blockIdx.x;      // row pair: rows 2b, 2b+1
    const int jq  = tid & 63;             // column quad
    const int g   = tid >> 6;             // k-group (0..15)
    const int j0  = jq << 2;

    // Per-thread W slice (same as R6): 64 fp32, pin-then-spill = the
    // proven ~220B/cy L2/scratch stream; now feeds BOTH rows' FMAs.
    const float* wp = Wh + (size_t)(g * 16) * HDIM + j0;
    LDW(0)  LDW(1)  LDW(2)  LDW(3)  LDW(4)  LDW(5)  LDW(6)  LDW(7)
    LDW(8)  LDW(9)  LDW(10) LDW(11) LDW(12) LDW(13) LDW(14) LDW(15)
    PIN16(wA); PIN16(wB); PIN16(wC); PIN16(wD);

    // h0 for both rows.
    if (tid < 512) hl[tid] = h0v[(size_t)(b * ROWS_PB) * HDIM + tid];

    // Per-thread c/out pointer (valid for tid<512): row = tid>>8, col = tid&255.
    float* outp = out + (size_t)(b * ROWS_PB + (tid >> 8)) * TSTEPS * HDIM + (tid & 255);
    __syncthreads();

    float c_next = 0.f;
    for (int ch = 0; ch < NCH; ++ch) {
        if (mode == 0) {
            if (tid == 0) {
                const unsigned int* f0 = &flags[(b * ROWS_PB) * NCH + ch];
                const unsigned int* f1 = &flags[(b * ROWS_PB + 1) * NCH + ch];
                while (__hip_atomic_load(f0, __ATOMIC_RELAXED,
                                         __HIP_MEMORY_SCOPE_AGENT) == 0u)
                    __builtin_amdgcn_s_sleep(8);
                while (__hip_atomic_load(f1, __ATOMIC_RELAXED,
                                         __HIP_MEMORY_SCOPE_AGENT) == 0u)
                    __builtin_amdgcn_s_sleep(8);
                (void)__hip_atomic_load(f1, __ATOMIC_ACQUIRE,
                                        __HIP_MEMORY_SCOPE_AGENT);
            }
            __syncthreads();    // acquire happens-before everyone's c reads
        }
        if (tid < 512) c_next = outp[(size_t)(ch * CH_STEPS) * HDIM];

        for (int tt = 0; tt < CH_STEPS; ++tt) {
            const int t = ch * CH_STEPS + tt;
            float c = c_next;
            if (tid < 512 && tt + 1 < CH_STEPS)   // stay inside gated chunk
                c_next = outp[(size_t)(t + 1) * HDIM];

            float h0, h1, h2, h3, h4, h5, h6, h7;
            float h8, h9, h10, h11, h12, h13, h14, h15;

            // Row A: acc over this thread's k-group x 4 cols.
            float a0 = 0.f, a1 = 0.f, a2 = 0.f, a3 = 0.f;
            LDH(hl);
            FMA64(a0, a1, a2, a3);
            float4 accA; accA.x = a0; accA.y = a1; accA.z = a2; accA.w = a3;
            *(float4*)&red[0][g][j0] = accA;

            // Row B: same W registers (the amortization), h from row B.
            a0 = 0.f; a1 = 0.f; a2 = 0.f; a3 = 0.f;
            LDH(hl + 256);
            FMA64(a0, a1, a2, a3);
            float4 accB; accB.x = a0; accB.y = a1; accB.z = a2; accB.w = a3;
            *(float4*)&red[1][g][j0] = accB;
            __syncthreads();

            if (tid < 512) {
                const int row = tid >> 8;
                const int col = tid & 255;
                float s0 = red[row][0][col] + red[row][1][col];
                float s1 = red[row][2][col] + red[row][3][col];
                float s2 = red[row][4][col] + red[row][5][col];
                float s3 = red[row][6][col] + red[row][7][col];
                float s4 = red[row][8][col] + red[row][9][col];
                float s5 = red[row][10][col] + red[row][11][col];
                float s6 = red[row][12][col] + red[row][13][col];
                float s7 = red[row][14][col] + red[row][15][col];
                float s  = (((s0 + s1) + (s2 + s3)) + ((s4 + s5) + (s6 + s7))) + c;
                float e  = __expf(2.f * s);
                float hn = 1.f - 2.f / (e + 1.f);
                outp[(size_t)t * HDIM] = hn;   // in-place: c was read above
                hl[tid] = hn;                  // safe: all FMA reads done (barrier)
            }
            __syncthreads();   // next step's FMA must see updated h
        }
    }
}

extern "C" void kernel_launch(void* const* d_in, const int* in_sizes, int n_in,
                              void* d_out, int out_size, void* d_ws, size_t ws_size,
                              hipStream_t stream) {
    const float* x  = (const float*)d_in[0];   // (64,512,256)
    const float* h0 = (const float*)d_in[1];   // (64,256)
    const float* Wx = (const float*)d_in[2];   // (256,256)
    const float* Wh = (const float*)d_in[3];   // (256,256)
    const float* b  = (const float*)d_in[4];   // (256)
    float* out = (float*)d_out;                // (64,512,256)

    const size_t flag_bytes = (size_t)NBATCH * NCH * sizeof(unsigned int);
    if (d_ws != nullptr && ws_size >= flag_bytes) {
        unsigned int* flags = (unsigned int*)d_ws;
        hipMemsetAsync(d_ws, 0, flag_bytes, stream);
        fused<<<SCAN_BLOCKS + GEMM_BLOCKS, 1024, 0, stream>>>(
            x, h0, Wx, Wh, b, out, flags, 0);
    } else {
        // Fallback: serialized two-pass.
        fused<<<SCAN_BLOCKS + GEMM_BLOCKS, 1024, 0, stream>>>(
            x, h0, Wx, Wh, b, out, nullptr, 1);
        fused<<<SCAN_BLOCKS, 1024, 0, stream>>>(
            x, h0, Wx, Wh, b, out, nullptr, 2);
    }
}